// Round 1
// baseline (542.070 us; speedup 1.0000x reference)
//
#include <hip/hip_runtime.h>
#include <hip/hip_bf16.h>

typedef float f32x4 __attribute__((ext_vector_type(4)));
typedef short s16x8 __attribute__((ext_vector_type(8)));
typedef short s16x4 __attribute__((ext_vector_type(4)));

#define NHID 128
#define OBS  64
#define LAT  32
#define KTOT 192        // OBS + NHID
#define BB   16         // batch rows per block
#define LDB  328        // ushorts per comb row: 64 x | 128 h(buf0) | 128 h(buf1) | 8 pad
                        // row stride 656 B: 16B-aligned, bank stride 164%32=4 -> 2-way (free)

static __device__ __forceinline__ unsigned short f2bf(float x) {
    __hip_bfloat16 h = __float2bfloat16(x);
    return *reinterpret_cast<unsigned short*>(&h);
}

static __device__ __forceinline__ float fast_tanh(float x) {
    float ax = __builtin_fabsf(x);
    float e  = __expf(-2.0f * ax);            // e^(-2|x|) in (0,1]; underflow -> tanh=1, safe
    float r  = __fdividef(1.0f - e, 1.0f + e);
    return __builtin_copysignf(r, x);
}

// One block = 16 batch rows, loops all T steps. 4 waves: wave w owns hidden
// units j in [32w, 32w+32) for the i2h GEMM; wave 0 also does h2o + store.
// h kept in LDS as bf16, double-buffered (2 barriers/step). W1/Wo live in
// registers as MFMA A-fragments for the whole kernel.
__global__ __launch_bounds__(256) void rnn_fused(
    const float* __restrict__ data,   // [B, T, OBS] f32
    const float* __restrict__ W1,     // [NHID, KTOT] f32
    const float* __restrict__ b1,     // [NHID]
    const float* __restrict__ Wo,     // [LAT, NHID] f32
    const float* __restrict__ bo,     // [LAT]
    float* __restrict__ out,          // [B, T, LAT] f32
    int T)
{
    __shared__ __align__(16) unsigned short comb[BB * LDB];

    const int tid  = threadIdx.x;
    const int wid  = tid >> 6;
    const int lane = tid & 63;
    const int lr   = lane & 15;   // A-row / B-col(b) / D-col(b)
    const int lg   = lane >> 4;   // 0..3
    const int b0   = blockIdx.x * BB;

    // ---- W1 A-fragments for this wave's j-chunk (32 rows = 2 j-tiles x 6 k-frags) ----
    // A[16x32] frag: lane l holds A[l&15][8*(l>>4)+i], i=0..7 (16B contiguous k)
    const int j0 = wid * 32;
    s16x8 w1f[2][6];
    float bi[2][4];
    for (int jt = 0; jt < 2; ++jt) {
        const float* wrow = W1 + (size_t)(j0 + jt * 16 + lr) * KTOT + lg * 8;
        for (int kf = 0; kf < 6; ++kf) {
            float4 a = *reinterpret_cast<const float4*>(wrow + kf * 32);
            float4 c = *reinterpret_cast<const float4*>(wrow + kf * 32 + 4);
            s16x8 f;
            f[0]=f2bf(a.x); f[1]=f2bf(a.y); f[2]=f2bf(a.z); f[3]=f2bf(a.w);
            f[4]=f2bf(c.x); f[5]=f2bf(c.y); f[6]=f2bf(c.z); f[7]=f2bf(c.w);
            w1f[jt][kf] = f;
        }
        // D layout: row = (lane>>4)*4 + r  [m89-verified]
        for (int r = 0; r < 4; ++r)
            bi[jt][r] = b1[j0 + jt * 16 + lg * 4 + r];
    }

    // ---- wave 0: Wo A-fragments (2 lat-tiles x 4 k-frags over NHID) ----
    s16x8 wof[2][4];
    float bof[2][4];
    if (wid == 0) {
        for (int lt = 0; lt < 2; ++lt) {
            const float* wrow = Wo + (size_t)(lt * 16 + lr) * NHID + lg * 8;
            for (int kt = 0; kt < 4; ++kt) {
                float4 a = *reinterpret_cast<const float4*>(wrow + kt * 32);
                float4 c = *reinterpret_cast<const float4*>(wrow + kt * 32 + 4);
                s16x8 f;
                f[0]=f2bf(a.x); f[1]=f2bf(a.y); f[2]=f2bf(a.z); f[3]=f2bf(a.w);
                f[4]=f2bf(c.x); f[5]=f2bf(c.y); f[6]=f2bf(c.z); f[7]=f2bf(c.w);
                wof[lt][kt] = f;
            }
            for (int r = 0; r < 4; ++r)
                bof[lt][r] = bo[lt * 16 + lg * 4 + r];
        }
    }

    // ---- init: zero h buffer 0 (h_{-1}=0), stage x_0 ----
    {
        int idx = tid * 8;            // 16*128 = 2048 ushorts, 8 per thread
        int b   = idx >> 7;
        int jj  = idx & 127;
        *reinterpret_cast<uint4*>(&comb[b * LDB + 64 + jj]) = make_uint4(0,0,0,0);
    }
    const int xb = tid >> 4;          // 0..15: batch row staged by this thread
    const int xk = (tid & 15) * 4;    // 4 obs elements
    {
        float4 x = *reinterpret_cast<const float4*>(
            data + ((size_t)(b0 + xb) * T + 0) * OBS + xk);
        s16x4 px;
        px[0]=f2bf(x.x); px[1]=f2bf(x.y); px[2]=f2bf(x.z); px[3]=f2bf(x.w);
        *reinterpret_cast<s16x4*>(&comb[xb * LDB + xk]) = px;
    }
    __syncthreads();

    // x prefetch pipeline, depth 2: xpA holds x_{t+1}, issued one iter early
    float4 xpA = *reinterpret_cast<const float4*>(
        data + ((size_t)(b0 + xb) * T + (T > 1 ? 1 : 0)) * OBS + xk);

    int p = 0;                        // current h buffer
    for (int t = 0; t < T; ++t) {
        // issue load of x_{t+2} (consumed at end of next iteration)
        int tn = (t + 2 < T) ? t + 2 : T - 1;
        float4 xpB = *reinterpret_cast<const float4*>(
            data + ((size_t)(b0 + xb) * T + tn) * OBS + xk);

        // B-fragments of comb^T: lane l reads comb[b=l&15][8*(l>>4)+i + 32*kf]
        const unsigned short* crow = comb + lr * LDB;
        s16x8 bfr[6];
        bfr[0] = *reinterpret_cast<const s16x8*>(crow + lg * 8);
        bfr[1] = *reinterpret_cast<const s16x8*>(crow + 32 + lg * 8);
        const int hoff = 64 + p * 128;
        for (int kf = 0; kf < 4; ++kf)
            bfr[2 + kf] = *reinterpret_cast<const s16x8*>(crow + hoff + kf * 32 + lg * 8);

        // i2h: D[j][b] = sum_k W1[j][k] * comb[b][k]  (acc fp32)
        f32x4 acc[2];
        for (int jt = 0; jt < 2; ++jt) {
            f32x4 a;
            a[0]=bi[jt][0]; a[1]=bi[jt][1]; a[2]=bi[jt][2]; a[3]=bi[jt][3];
            for (int kf = 0; kf < 6; ++kf)
                a = __builtin_amdgcn_mfma_f32_16x16x32_bf16(w1f[jt][kf], bfr[kf], a, 0, 0, 0);
            acc[jt] = a;
        }

        // tanh (fp32) -> h_new bf16 into buffer 1-p (disjoint from all live reads)
        const int hw_off = 64 + (1 - p) * 128;
        for (int jt = 0; jt < 2; ++jt) {
            s16x4 hw;
            for (int r = 0; r < 4; ++r)
                hw[r] = f2bf(fast_tanh(acc[jt][r]));
            *reinterpret_cast<s16x4*>(
                &comb[lr * LDB + hw_off + j0 + jt * 16 + lg * 4]) = hw;
        }
        __syncthreads();   // h_new visible; all reads of x_t / h_{t-1} retired

        // h2o on wave 0: Out^T[lat][b] = Wo . h_new^T ; direct f32 store
        if (wid == 0) {
            s16x8 hf[4];
            const unsigned short* hrow = comb + lr * LDB + hw_off;
            for (int kt = 0; kt < 4; ++kt)
                hf[kt] = *reinterpret_cast<const s16x8*>(hrow + kt * 32 + lg * 8);
            for (int lt = 0; lt < 2; ++lt) {
                f32x4 o;
                o[0]=bof[lt][0]; o[1]=bof[lt][1]; o[2]=bof[lt][2]; o[3]=bof[lt][3];
                for (int kt = 0; kt < 4; ++kt)
                    o = __builtin_amdgcn_mfma_f32_16x16x32_bf16(wof[lt][kt], hf[kt], o, 0, 0, 0);
                float4 st;
                st.x=o[0]; st.y=o[1]; st.z=o[2]; st.w=o[3];
                // lanes {l, l+16, l+32, l+48} cover one full 64B line of out[b][t][:]
                *reinterpret_cast<float4*>(
                    out + ((size_t)(b0 + lr) * T + t) * LAT + lt * 16 + lg * 4) = st;
            }
        }

        // write x_{t+1} into x region (its readers all retired at the barrier above)
        {
            s16x4 px;
            px[0]=f2bf(xpA.x); px[1]=f2bf(xpA.y); px[2]=f2bf(xpA.z); px[3]=f2bf(xpA.w);
            *reinterpret_cast<s16x4*>(&comb[xb * LDB + xk]) = px;
        }
        xpA = xpB;
        __syncthreads();   // x_{t+1} visible; wave0's h2o reads retired
        p ^= 1;
    }
}

extern "C" void kernel_launch(void* const* d_in, const int* in_sizes, int n_in,
                              void* d_out, int out_size, void* d_ws, size_t ws_size,
                              hipStream_t stream) {
    const float* data = (const float*)d_in[0];
    const float* W1   = (const float*)d_in[1];
    const float* b1   = (const float*)d_in[2];
    const float* Wo   = (const float*)d_in[3];
    const float* bo   = (const float*)d_in[4];
    float* out = (float*)d_out;

    const int B = 4096;                       // fixed by the benchmark
    const int T = in_sizes[0] / (B * OBS);    // time_dim derivable host-side

    dim3 grid(B / BB);                        // 256 blocks -> 1 per CU
    rnn_fused<<<grid, 256, 0, stream>>>(data, W1, b1, Wo, bo, out, T);
}